// Round 5
// baseline (275.983 us; speedup 1.0000x reference)
//
#include <hip/hip_runtime.h>
#include <stdint.h>

// DILATE loss, B=32, L=512, DIM=16, gamma=1e-3, alpha=0.5.
//
// Round-5 structure:
//   kA : D[b][j][i] column-major (unchanged, ~20us).
//   kFG: one wave per batch.
//     Forward hard-min DP wavefront (lane l owns rows 8l+1..8l+8), phase-split:
//       prologue t=0..63 (clamped), steady t=64..503 (no validity checks,
//       pointer-increment addressing), epilogue t=504..575. Issue-bound fix.
//     Dir codes: 2 bits/cell (bit0 = diag-eq, bit1 = up-eq; decode priority
//       diag > up > left), packed 4x4 cells per u32 tile word in LDS:
//       dirT[ctile][rowtile], ctile=col0>>2 (128=dump), rowtile=row0>>2.
//       bit pos = 8*(col0&3) + 2*(row0&3). One ds_write_b64 per step.
//     Backward = PATH TRACE (E is the argmin-path indicator at gamma->0):
//       serial walk (N,N)->(1,1) following dirs, accumulating (i-j)^2.
//       3 neighbor tiles speculatively prefetched per tile entry.
//   kC : combine -> scalar loss.

#define N 512
#define NB 32
#define BIGF 1e10f

typedef unsigned int u32;

// ---------------- kA: pairwise squared distances, column-major -------------
__global__ __launch_bounds__(512) void kA(const float* __restrict__ inp,
                                          const float* __restrict__ tgt,
                                          float* __restrict__ Dg) {
    const int b = blockIdx.y;
    const int jc = blockIdx.x;         // group of 4 columns
    const int tid = (int)threadIdx.x;  // row index i0 in [0,512)
    __shared__ float xs[4][16];        // x[j] = inp[b,j]-inp[b,0]
    if (tid < 64) {
        int c = tid >> 4, d = tid & 15;
        int j = jc * 4 + c;
        xs[c][d] = inp[(((size_t)b * N + j) << 4) + d] -
                   inp[(((size_t)b * N) << 4) + d];
    }
    __syncthreads();
    const float4* t4 = (const float4*)(tgt + (((size_t)b * N + tid) << 4));
    float4 ta = t4[0], tb = t4[1], tc = t4[2], td = t4[3];
    float* out = Dg + ((size_t)b * N + (size_t)jc * 4) * N + tid;
#pragma unroll
    for (int c = 0; c < 4; ++c) {
        float s = 0.f, e;
        e = ta.x - xs[c][0];  s = fmaf(e, e, s);
        e = ta.y - xs[c][1];  s = fmaf(e, e, s);
        e = ta.z - xs[c][2];  s = fmaf(e, e, s);
        e = ta.w - xs[c][3];  s = fmaf(e, e, s);
        e = tb.x - xs[c][4];  s = fmaf(e, e, s);
        e = tb.y - xs[c][5];  s = fmaf(e, e, s);
        e = tb.z - xs[c][6];  s = fmaf(e, e, s);
        e = tb.w - xs[c][7];  s = fmaf(e, e, s);
        e = tc.x - xs[c][8];  s = fmaf(e, e, s);
        e = tc.y - xs[c][9];  s = fmaf(e, e, s);
        e = tc.z - xs[c][10]; s = fmaf(e, e, s);
        e = tc.w - xs[c][11]; s = fmaf(e, e, s);
        e = td.x - xs[c][12]; s = fmaf(e, e, s);
        e = td.y - xs[c][13]; s = fmaf(e, e, s);
        e = td.z - xs[c][14]; s = fmaf(e, e, s);
        e = td.w - xs[c][15]; s = fmaf(e, e, s);
        out[(size_t)c * N] = s;
    }
}

// ---------------- kFG: forward DP + path trace, one wave per batch ---------
__global__ __launch_bounds__(64) void kFG(const float* __restrict__ Dg,
                                          float* __restrict__ acc) {
    const int b = blockIdx.x;
    const int l = (int)threadIdx.x;
    const float* Db = Dg + (size_t)b * N * N;

    __shared__ u32 dirT[129 * 128];  // [col-tile 0..127, 128=dump][row-tile]

    // ================= forward =================
    float Rprev[8];
#pragma unroll
    for (int r = 0; r < 8; ++r) Rprev[r] = BIGF;
    float aN = BIGF, bV = BIGF, Rfin = 0.f;
    u32 wLo = 0, wHi = 0;
    float4 Pa[8], Pb[8];

#define PFC(k, t)                                                             \
    do {                                                                      \
        int j0_ = min(max((t) - l, 0), N - 1);                                \
        const float4* p_ = (const float4*)(Db + ((size_t)j0_ << 9) + (l << 3)); \
        Pa[k] = p_[0]; Pb[k] = p_[1];                                         \
    } while (0)

#pragma unroll
    for (int k = 0; k < 8; ++k) PFC(k, k);

    // generic step: validity checks + clamped behavior (prologue/epilogue)
#define GEN_STEP(t, k)                                                        \
    do {                                                                      \
        const int j0 = (t) - l;                                               \
        const bool valid = (unsigned)j0 < (unsigned)N;                        \
        const float a0 = (l == 0) ? BIGF : aN;                                \
        const float b0 = (l == 0) ? (((t) == 0) ? 0.f : BIGF) : bV;           \
        float dd[8] = {Pa[k].x, Pa[k].y, Pa[k].z, Pa[k].w,                    \
                       Pb[k].x, Pb[k].y, Pb[k].z, Pb[k].w};                   \
        float Rc[8]; u32 nLo = 0, nHi = 0;                                    \
        const u32 sh8 = (u32)(j0 & 3) << 3;                                   \
        _Pragma("unroll") for (int r = 0; r < 8; ++r) {                       \
            float up = (r == 0) ? a0 : Rc[r - 1];                             \
            float dg = (r == 0) ? b0 : Rprev[r - 1];                          \
            float lf = Rprev[r];                                              \
            float mn = fminf(up, fminf(dg, lf));                              \
            Rc[r] = dd[r] + mn;                                               \
            u32 bits = ((mn == dg) ? 1u : 0u) | ((mn == up) ? 2u : 0u);       \
            if (r < 4) nLo |= bits << (sh8 + 2 * r);                          \
            else       nHi |= bits << (sh8 + 2 * (r - 4));                    \
        }                                                                     \
        wLo = ((j0 & 3) == 0) ? nLo : (wLo | nLo);                            \
        wHi = ((j0 & 3) == 0) ? nHi : (wHi | nHi);                            \
        const int ctile = valid ? (j0 >> 2) : 128;                            \
        *(uint2*)&dirT[ctile * 128 + 2 * l] = make_uint2(wLo, wHi);           \
        _Pragma("unroll") for (int r = 0; r < 8; ++r)                         \
            Rprev[r] = valid ? Rc[r] : Rprev[r];                              \
        if (j0 == N - 1) Rfin = Rc[7];                                        \
        float expv = valid ? Rc[7] : BIGF;                                    \
        bV = aN; aN = __shfl_up(expv, 1);                                     \
    } while (0)

    // steady step: all lanes valid, no clamps, pointer-increment loads
#define STD_STEP(t, k)                                                        \
    do {                                                                      \
        const int j0 = (t) - l;                                               \
        const float a0 = (l == 0) ? BIGF : aN;                                \
        const float b0 = (l == 0) ? BIGF : bV;                                \
        float dd[8] = {Pa[k].x, Pa[k].y, Pa[k].z, Pa[k].w,                    \
                       Pb[k].x, Pb[k].y, Pb[k].z, Pb[k].w};                   \
        float Rc[8]; u32 nLo = 0, nHi = 0;                                    \
        const u32 sh8 = (u32)(j0 & 3) << 3;                                   \
        _Pragma("unroll") for (int r = 0; r < 8; ++r) {                       \
            float up = (r == 0) ? a0 : Rc[r - 1];                             \
            float dg = (r == 0) ? b0 : Rprev[r - 1];                          \
            float lf = Rprev[r];                                              \
            float mn = fminf(up, fminf(dg, lf));                              \
            Rc[r] = dd[r] + mn;                                               \
            u32 bits = ((mn == dg) ? 1u : 0u) | ((mn == up) ? 2u : 0u);       \
            if (r < 4) nLo |= bits << (sh8 + 2 * r);                          \
            else       nHi |= bits << (sh8 + 2 * (r - 4));                    \
        }                                                                     \
        wLo = ((j0 & 3) == 0) ? nLo : (wLo | nLo);                            \
        wHi = ((j0 & 3) == 0) ? nHi : (wHi | nHi);                            \
        *(uint2*)&dirT[(j0 >> 2) * 128 + 2 * l] = make_uint2(wLo, wHi);       \
        _Pragma("unroll") for (int r = 0; r < 8; ++r) Rprev[r] = Rc[r];       \
        bV = aN; aN = __shfl_up(Rc[7], 1);                                    \
        Pa[k] = ((const float4*)pk[k])[0];                                    \
        Pb[k] = ((const float4*)pk[k])[1];                                    \
        pk[k] += 8 * 512;                                                     \
    } while (0)

    // prologue: t = 0..63
    for (int t0 = 0; t0 < 64; t0 += 8) {
#pragma unroll
        for (int k = 0; k < 8; ++k) { GEN_STEP(t0 + k, k); PFC(k, t0 + k + 8); }
    }
    // steady: t = 64..503 (all lanes valid; prefetch cols 72..511 unclamped)
    const float* pk[8];
#pragma unroll
    for (int k = 0; k < 8; ++k)
        pk[k] = Db + ((size_t)(72 + k - l) << 9) + (l << 3);
    for (int t0 = 64; t0 < 504; t0 += 8) {
#pragma unroll
        for (int k = 0; k < 8; ++k) { STD_STEP(t0 + k, k); }
    }
    // epilogue: t = 504..575
    for (int t0 = 504; t0 < 576; t0 += 8) {
#pragma unroll
        for (int k = 0; k < 8; ++k) { GEN_STEP(t0 + k, k); PFC(k, t0 + k + 8); }
    }
#undef GEN_STEP
#undef STD_STEP
#undef PFC

    if (l == 63) acc[b] = Rfin;  // Rp[N,N]: DTW value

    asm volatile("s_waitcnt lgkmcnt(0)" ::: "memory");

    // ================= backward: path trace =================
    // All lanes run the identical trace (uniform branches, LDS broadcast).
    {
        int i = N, j = N;
        float tsum = 0.f;  // (N-N)^2 = 0 for start cell
        int rt = 127, ct = 127;
        u32 w = dirT[ct * 128 + rt];
        bool done = false;
        for (int g = 0; g < 1100 && !done; ++g) {
            // speculative prefetch of the 3 possible next tiles
            const int rtm = rt > 0 ? rt - 1 : 0;
            const int ctm = ct > 0 ? ct - 1 : 0;
            u32 wU = dirT[ct * 128 + rtm];
            u32 wL = dirT[ctm * 128 + rt];
            u32 wD = dirT[ctm * 128 + rtm];
            while (true) {
                const int row0 = i - 1, col0 = j - 1;
                const u32 sh = ((u32)(col0 & 3) << 3) | ((u32)(row0 & 3) << 1);
                const u32 bits = (w >> sh) & 3u;
                // bits: 1/3 = diag, 2 = up, 0 = left (priority diag>up>left)
                const int di = (int)((bits | (bits >> 1)) & 1u);
                const int dj = (int)((bits & 1u) | (bits == 0u ? 1u : 0u));
                i -= di; j -= dj;
                const int d = i - j;
                tsum += (float)(d * d);
                if ((i | j) == 1) { done = true; break; }  // reached (1,1)
                const int nrt = (i - 1) >> 2, nct = (j - 1) >> 2;
                if ((nrt != rt) || (nct != ct)) {
                    w = (nct != ct) ? ((nrt != rt) ? wD : wL) : wU;
                    rt = nrt; ct = nct;
                    break;  // re-prefetch neighbors
                }
            }
        }
        if (l == 0) acc[NB + b] = tsum;
    }
}

// ---------------- kC: combine over batches ---------------------------------
__global__ void kC(const float* __restrict__ acc, float* __restrict__ out) {
    const int l = (int)threadIdx.x;
    float vs = (l < NB) ? acc[l] : 0.f;
    float vt = (l < NB) ? acc[NB + l] : 0.f;
#pragma unroll
    for (int o = 32; o >= 1; o >>= 1) {
        vs += __shfl_down(vs, o);
        vt += __shfl_down(vt, o);
    }
    if (l == 0)
        out[0] = 0.5f * (vs / (float)NB) +
                 0.5f * (vt / ((float)NB * (float)(N * N)));
}

__global__ void kSentinel(float* out) { out[0] = -12345.0f; }

extern "C" void kernel_launch(void* const* d_in, const int* in_sizes, int n_in,
                              void* d_out, int out_size, void* d_ws, size_t ws_size,
                              hipStream_t stream) {
    const float* inp = (const float*)d_in[0];
    const float* tgt = (const float*)d_in[1];
    float* out = (float*)d_out;

    const size_t DSZ = (size_t)NB * N * N * sizeof(float);  // 32 MiB
    const size_t NEEDED = 256 + DSZ;
    if (ws_size < NEEDED) {
        kSentinel<<<1, 1, 0, stream>>>(out);
        return;
    }
    char* ws = (char*)d_ws;
    float* acc = (float*)ws;  // [0..31] shape, [32..63] temporal
    float* Dg = (float*)(ws + 256);

    kA<<<dim3(N / 4, NB), 512, 0, stream>>>(inp, tgt, Dg);
    kFG<<<NB, 64, 0, stream>>>(Dg, acc);
    kC<<<1, 64, 0, stream>>>(acc, out);
}